// Round 1
// baseline (2245.747 us; speedup 1.0000x reference)
//
#include <hip/hip_runtime.h>
#include <math.h>

constexpr int N_NODES = 40000;
constexpr int N_EDGES = 500000;
constexpr int ETOT    = N_EDGES + N_NODES;
constexpr int IN_DIM  = 128;
constexpr int ED_DIM  = 16;
constexpr int FEAT    = 256;   // H*C for every layer
constexpr int BATCH   = 128;
constexpr float NEG   = 0.2f;
constexpr int NCHUNK  = (N_NODES + 255) / 256;  // 157

// ---------------- self-loop mean edge attr ----------------
__global__ __launch_bounds__(256) void k_loop_accum(const int* __restrict__ dst,
    const float* __restrict__ ea, float* __restrict__ lsum, float* __restrict__ cnt)
{
    int t = blockIdx.x * 256 + threadIdx.x;
    if (t >= N_EDGES * ED_DIM) return;
    int e = t >> 4, d = t & 15;
    int v = dst[e];
    atomicAdd(&lsum[v * ED_DIM + d], ea[t]);
    if (d == 0) atomicAdd(&cnt[v], 1.0f);
}

__global__ __launch_bounds__(256) void k_loop_final(const float* __restrict__ lsum,
    const float* __restrict__ cnt, float* __restrict__ loop_attr)
{
    int t = blockIdx.x * 256 + threadIdx.x;
    if (t >= N_NODES * ED_DIM) return;
    int n = t >> 4;
    float c = fmaxf(cnt[n], 1.0f);
    loop_attr[t] = lsum[t] / c;
}

// ---------------- CSR build (by dst, incl. self loops) ----------------
__global__ __launch_bounds__(256) void k_deg(const int* __restrict__ dst, int* __restrict__ deg)
{
    int e = blockIdx.x * 256 + threadIdx.x;
    if (e >= ETOT) return;
    int v = e < N_EDGES ? dst[e] : e - N_EDGES;
    atomicAdd(&deg[v], 1);
}

__global__ __launch_bounds__(256) void k_scan1(const int* __restrict__ deg, int* __restrict__ bsum)
{
    __shared__ int s[256];
    int t = threadIdx.x;
    int idx = blockIdx.x * 256 + t;
    s[t] = idx < N_NODES ? deg[idx] : 0;
    __syncthreads();
    for (int st = 128; st; st >>= 1) { if (t < st) s[t] += s[t + st]; __syncthreads(); }
    if (t == 0) bsum[blockIdx.x] = s[0];
}

__global__ __launch_bounds__(256) void k_scan2(const int* __restrict__ bsum,
    int* __restrict__ boff, int* __restrict__ rowptr)
{
    __shared__ int s[256];
    int t = threadIdx.x;
    int v = t < NCHUNK ? bsum[t] : 0;
    s[t] = v;
    __syncthreads();
    for (int off = 1; off < 256; off <<= 1) {
        int x = (t >= off) ? s[t - off] : 0;
        __syncthreads();
        s[t] += x;
        __syncthreads();
    }
    if (t < NCHUNK) boff[t] = s[t] - v;
    if (t == 0) rowptr[N_NODES] = ETOT;
}

__global__ __launch_bounds__(256) void k_scan3(const int* __restrict__ deg,
    const int* __restrict__ boff, int* __restrict__ rowptr)
{
    __shared__ int s[256];
    int t = threadIdx.x;
    int idx = blockIdx.x * 256 + t;
    int v = idx < N_NODES ? deg[idx] : 0;
    s[t] = v;
    __syncthreads();
    for (int off = 1; off < 256; off <<= 1) {
        int x = (t >= off) ? s[t - off] : 0;
        __syncthreads();
        s[t] += x;
        __syncthreads();
    }
    if (idx < N_NODES) rowptr[idx] = boff[blockIdx.x] + s[t] - v;
}

__global__ __launch_bounds__(256) void k_fill(const int* __restrict__ dst,
    const int* __restrict__ rowptr, int* __restrict__ fill, int* __restrict__ elist)
{
    int e = blockIdx.x * 256 + threadIdx.x;
    if (e >= ETOT) return;
    int v = e < N_EDGES ? dst[e] : e - N_EDGES;
    int pos = rowptr[v] + atomicAdd(&fill[v], 1);
    elist[pos] = e;
}

// ---------------- fp32 tiled GEMM: C[M,N] = A[M,K] @ W[K,N] + bias (+relu) ----------------
__global__ __launch_bounds__(256) void k_gemm(const float* __restrict__ A, const float* __restrict__ W,
    const float* __restrict__ bias, float* __restrict__ C, int M, int N, int K, int act)
{
    __shared__ float As[16][65];
    __shared__ float Ws[16][65];
    int t = threadIdx.x;
    int bm = blockIdx.x * 64, bn = blockIdx.y * 64;
    int tm = (t >> 4) << 2, tn = (t & 15) << 2;
    int am = t >> 2, ak4 = (t & 3) << 2;
    int wk = t >> 4, wn4 = (t & 15) << 2;
    float acc[4][4] = {};
    for (int k0 = 0; k0 < K; k0 += 16) {
        float4 av = *reinterpret_cast<const float4*>(A + (size_t)(bm + am) * K + k0 + ak4);
        float4 wv = *reinterpret_cast<const float4*>(W + (size_t)(wk + k0) * N + bn + wn4);
        As[ak4 + 0][am] = av.x; As[ak4 + 1][am] = av.y; As[ak4 + 2][am] = av.z; As[ak4 + 3][am] = av.w;
        Ws[wk][wn4 + 0] = wv.x; Ws[wk][wn4 + 1] = wv.y; Ws[wk][wn4 + 2] = wv.z; Ws[wk][wn4 + 3] = wv.w;
        __syncthreads();
        #pragma unroll
        for (int k = 0; k < 16; ++k) {
            float a0 = As[k][tm + 0], a1 = As[k][tm + 1], a2 = As[k][tm + 2], a3 = As[k][tm + 3];
            float b0 = Ws[k][tn + 0], b1 = Ws[k][tn + 1], b2 = Ws[k][tn + 2], b3 = Ws[k][tn + 3];
            acc[0][0] += a0 * b0; acc[0][1] += a0 * b1; acc[0][2] += a0 * b2; acc[0][3] += a0 * b3;
            acc[1][0] += a1 * b0; acc[1][1] += a1 * b1; acc[1][2] += a1 * b2; acc[1][3] += a1 * b3;
            acc[2][0] += a2 * b0; acc[2][1] += a2 * b1; acc[2][2] += a2 * b2; acc[2][3] += a2 * b3;
            acc[3][0] += a3 * b0; acc[3][1] += a3 * b1; acc[3][2] += a3 * b2; acc[3][3] += a3 * b3;
        }
        __syncthreads();
    }
    #pragma unroll
    for (int i = 0; i < 4; ++i) {
        float4 v;
        v.x = acc[i][0] + bias[bn + tn + 0];
        v.y = acc[i][1] + bias[bn + tn + 1];
        v.z = acc[i][2] + bias[bn + tn + 2];
        v.w = acc[i][3] + bias[bn + tn + 3];
        if (act) { v.x = fmaxf(v.x, 0.f); v.y = fmaxf(v.y, 0.f); v.z = fmaxf(v.z, 0.f); v.w = fmaxf(v.w, 0.f); }
        *reinterpret_cast<float4*>(C + (size_t)(bm + tm + i) * N + bn + tn) = v;
    }
}

static void launch_gemm(const float* A, const float* W, const float* bias, float* C,
                        int M, int N, int K, int act, hipStream_t stream)
{
    dim3 grid(M / 64, N / 64);
    k_gemm<<<grid, 256, 0, stream>>>(A, W, bias, C, M, N, K, act);
}

// ---------------- fused GATv2 edge+softmax+aggregate: one wave per dst node ----------------
template <int H, int RELU>
__global__ __launch_bounds__(256) void k_gat(
    const float* __restrict__ xl, const float* __restrict__ xr,
    const float* __restrict__ ea, const float* __restrict__ loop_attr,
    const int* __restrict__ srcArr, const int* __restrict__ elist, const int* __restrict__ rowptr,
    const float* __restrict__ We, const float* __restrict__ att,
    const float* __restrict__ bias, float* __restrict__ out)
{
    __shared__ float sWe[ED_DIM * FEAT];
    __shared__ float sAtt[FEAT];
    int t = threadIdx.x;
    #pragma unroll
    for (int i = 0; i < ED_DIM; ++i) sWe[i * 256 + t] = We[i * 256 + t];
    sAtt[t] = att[t];
    __syncthreads();

    int lane = t & 63;
    int n = blockIdx.x * 4 + (t >> 6);

    float xrv[4], acc[4] = {0.f, 0.f, 0.f, 0.f};
    #pragma unroll
    for (int j = 0; j < 4; ++j) xrv[j] = xr[(size_t)n * FEAT + lane + 64 * j];

    float m[H], z[H];
    #pragma unroll
    for (int h = 0; h < H; ++h) { m[h] = -INFINITY; z[h] = 0.f; }

    int p0 = rowptr[n], p1 = rowptr[n + 1];
    for (int p = p0; p < p1; ++p) {
        int e = elist[p];
        int src;
        const float* eav;
        if (e < N_EDGES) { src = srcArr[e]; eav = ea + (size_t)e * ED_DIM; }
        else             { src = e - N_EDGES; eav = loop_attr + (size_t)src * ED_DIM; }

        float xlv[4];
        #pragma unroll
        for (int j = 0; j < 4; ++j) xlv[j] = xl[(size_t)src * FEAT + lane + 64 * j];

        float ef[4] = {0.f, 0.f, 0.f, 0.f};
        #pragma unroll
        for (int d = 0; d < ED_DIM; ++d) {
            float a = eav[d];
            #pragma unroll
            for (int j = 0; j < 4; ++j) ef[j] += a * sWe[d * 256 + lane + 64 * j];
        }

        float pr[4];
        #pragma unroll
        for (int j = 0; j < 4; ++j) {
            float s = xlv[j] + xrv[j] + ef[j];
            s = s > 0.f ? s : NEG * s;
            pr[j] = s * sAtt[lane + 64 * j];
        }

        float l[H];
        if constexpr (H == 4) {
            #pragma unroll
            for (int j = 0; j < 4; ++j) l[j] = pr[j];
        } else {
            l[0] = pr[0] + pr[1] + pr[2] + pr[3];
        }
        #pragma unroll
        for (int off = 32; off > 0; off >>= 1) {
            #pragma unroll
            for (int h = 0; h < H; ++h) l[h] += __shfl_xor(l[h], off, 64);
        }

        float w[H], sc[H];
        #pragma unroll
        for (int h = 0; h < H; ++h) {
            float nm = fmaxf(m[h], l[h]);
            sc[h] = expf(m[h] - nm);
            w[h]  = expf(l[h] - nm);
            z[h]  = z[h] * sc[h] + w[h];
            m[h]  = nm;
        }
        #pragma unroll
        for (int j = 0; j < 4; ++j) {
            int h = (H == 4) ? j : 0;
            acc[j] = acc[j] * sc[h] + w[h] * xlv[j];
        }
    }

    #pragma unroll
    for (int j = 0; j < 4; ++j) {
        int h = (H == 4) ? j : 0;
        int idx = lane + 64 * j;
        float o = acc[j] / (z[h] + 1e-16f) + bias[idx];
        if (RELU) o = fmaxf(o, 0.f);
        out[(size_t)n * FEAT + idx] = o;
    }
}

// ---------------- gate score: gate[n] = ghid[n,:] @ W2 + b2 ----------------
__global__ __launch_bounds__(256) void k_gate_score(const float* __restrict__ ghid,
    const float* __restrict__ W2, const float* __restrict__ b2, float* __restrict__ gate)
{
    int lane = threadIdx.x & 63;
    int n = blockIdx.x * 4 + (threadIdx.x >> 6);
    float v = ghid[(size_t)n * 128 + lane] * W2[lane] + ghid[(size_t)n * 128 + lane + 64] * W2[lane + 64];
    #pragma unroll
    for (int off = 32; off > 0; off >>= 1) v += __shfl_xor(v, off, 64);
    if (lane == 0) gate[n] = v + b2[0];
}

// ---------------- attentional pooling: one block per batch segment ----------------
__device__ __forceinline__ int lbound(const int* a, int n, int v)
{
    int lo = 0, hi = n;
    while (lo < hi) { int mid = (lo + hi) >> 1; if (a[mid] < v) lo = mid + 1; else hi = mid; }
    return lo;
}

__global__ __launch_bounds__(256) void k_pool(const float* __restrict__ gate,
    const float* __restrict__ h, const int* __restrict__ batch, float* __restrict__ g)
{
    int b = blockIdx.x;
    int t = threadIdx.x;
    __shared__ float red[256];
    int start = lbound(batch, N_NODES, b);
    int end   = lbound(batch, N_NODES, b + 1);

    float mx = -INFINITY;
    for (int n = start + t; n < end; n += 256) mx = fmaxf(mx, gate[n]);
    red[t] = mx; __syncthreads();
    for (int s = 128; s; s >>= 1) { if (t < s) red[t] = fmaxf(red[t], red[t + s]); __syncthreads(); }
    float m = red[0];
    __syncthreads();

    float zs = 0.f;
    for (int n = start + t; n < end; n += 256) zs += expf(gate[n] - m);
    red[t] = zs; __syncthreads();
    for (int s = 128; s; s >>= 1) { if (t < s) red[t] += red[t + s]; __syncthreads(); }
    float z = red[0];

    float gs = 0.f;
    for (int n = start; n < end; ++n) gs += expf(gate[n] - m) * h[(size_t)n * FEAT + t];
    g[b * FEAT + t] = gs / (z + 1e-16f);
}

// ---------------- regression head: per-batch tiny MLP ----------------
__global__ __launch_bounds__(128) void k_reg(const float* __restrict__ g,
    const float* __restrict__ W1, const float* __restrict__ b1,
    const float* __restrict__ W2, const float* __restrict__ b2, float* __restrict__ out)
{
    int b = blockIdx.x, t = threadIdx.x;
    __shared__ float sg[FEAT];
    sg[t] = g[b * FEAT + t];
    sg[t + 128] = g[b * FEAT + t + 128];
    __syncthreads();
    float hv = b1[t];
    for (int k = 0; k < FEAT; ++k) hv += sg[k] * W1[k * 128 + t];
    hv = fmaxf(hv, 0.f);
    __shared__ float p0s[128], p1s[128];
    p0s[t] = hv * W2[t * 2 + 0];
    p1s[t] = hv * W2[t * 2 + 1];
    __syncthreads();
    for (int s = 64; s; s >>= 1) {
        if (t < s) { p0s[t] += p0s[t + s]; p1s[t] += p1s[t + s]; }
        __syncthreads();
    }
    if (t == 0) { out[b * 2 + 0] = p0s[0] + b2[0]; out[b * 2 + 1] = p1s[0] + b2[1]; }
}

// ---------------- launch ----------------
extern "C" void kernel_launch(void* const* d_in, const int* in_sizes, int n_in,
                              void* d_out, int out_size, void* d_ws, size_t ws_size,
                              hipStream_t stream)
{
    const float* x       = (const float*)d_in[0];
    const int*   ei      = (const int*)d_in[1];   // [2,E]
    const float* ea      = (const float*)d_in[2];
    const int*   batch   = (const int*)d_in[3];
    const float* c1_Wl   = (const float*)d_in[5];
    const float* c1_bl   = (const float*)d_in[6];
    const float* c1_Wr   = (const float*)d_in[7];
    const float* c1_br   = (const float*)d_in[8];
    const float* c1_We   = (const float*)d_in[9];
    const float* c1_att  = (const float*)d_in[10];
    const float* c1_bias = (const float*)d_in[11];
    const float* c2_Wl   = (const float*)d_in[12];
    const float* c2_bl   = (const float*)d_in[13];
    const float* c2_Wr   = (const float*)d_in[14];
    const float* c2_br   = (const float*)d_in[15];
    const float* c2_We   = (const float*)d_in[16];
    const float* c2_att  = (const float*)d_in[17];
    const float* c2_bias = (const float*)d_in[18];
    const float* c3_Wl   = (const float*)d_in[19];
    const float* c3_bl   = (const float*)d_in[20];
    const float* c3_Wr   = (const float*)d_in[21];
    const float* c3_br   = (const float*)d_in[22];
    const float* c3_We   = (const float*)d_in[23];
    const float* c3_att  = (const float*)d_in[24];
    const float* c3_bias = (const float*)d_in[25];
    const float* gate_W1 = (const float*)d_in[26];
    const float* gate_b1 = (const float*)d_in[27];
    const float* gate_W2 = (const float*)d_in[28];
    const float* gate_b2 = (const float*)d_in[29];
    const float* reg_W1  = (const float*)d_in[30];
    const float* reg_b1  = (const float*)d_in[31];
    const float* reg_W2  = (const float*)d_in[32];
    const float* reg_b2  = (const float*)d_in[33];

    const int* srcArr = ei;            // row 0
    const int* dstArr = ei + N_EDGES;  // row 1

    float* ws = (float*)d_ws;
    size_t off = 0;
    auto alloc = [&](size_t nf) { float* p = ws + off; off += (nf + 63) & ~(size_t)63; return p; };
    float* xl        = alloc((size_t)N_NODES * FEAT);
    float* xr        = alloc((size_t)N_NODES * FEAT);
    float* h         = alloc((size_t)N_NODES * FEAT);
    float* loop_attr = alloc((size_t)N_NODES * ED_DIM);
    float* gpool     = alloc((size_t)BATCH * FEAT);
    int* ibase  = (int*)(ws + off);
    int* deg    = ibase;
    int* fill   = ibase + N_NODES;
    int* rowptr = ibase + 2 * N_NODES;            // N+1 ints
    int* bsum   = ibase + 3 * N_NODES + 64;
    int* boff   = bsum + 256;
    int* elist  = boff + 256;

    // aliases at disjoint lifetimes
    float* lsum = xl;                       // before any GEMM
    float* cnt  = xl + N_NODES * ED_DIM;
    float* ghid = xl;                       // after L3 gat, xl is dead
    float* gate = xr;

    hipMemsetAsync(lsum, 0, (size_t)(N_NODES * ED_DIM + N_NODES) * sizeof(float), stream);
    hipMemsetAsync(deg, 0, (size_t)2 * N_NODES * sizeof(int), stream);

    // self-loop attrs + CSR
    k_loop_accum<<<(N_EDGES * ED_DIM + 255) / 256, 256, 0, stream>>>(dstArr, ea, lsum, cnt);
    k_loop_final<<<(N_NODES * ED_DIM + 255) / 256, 256, 0, stream>>>(lsum, cnt, loop_attr);
    k_deg<<<(ETOT + 255) / 256, 256, 0, stream>>>(dstArr, deg);
    k_scan1<<<NCHUNK, 256, 0, stream>>>(deg, bsum);
    k_scan2<<<1, 256, 0, stream>>>(bsum, boff, rowptr);
    k_scan3<<<NCHUNK, 256, 0, stream>>>(deg, boff, rowptr);
    k_fill<<<(ETOT + 255) / 256, 256, 0, stream>>>(dstArr, rowptr, fill, elist);

    // layer 1 (in: x [N,128])
    launch_gemm(x, c1_Wl, c1_bl, xl, N_NODES, FEAT, IN_DIM, 0, stream);
    launch_gemm(x, c1_Wr, c1_br, xr, N_NODES, FEAT, IN_DIM, 0, stream);
    k_gat<4, 1><<<N_NODES / 4, 256, 0, stream>>>(xl, xr, ea, loop_attr, srcArr, elist, rowptr,
                                                 c1_We, c1_att, c1_bias, h);
    // layer 2
    launch_gemm(h, c2_Wl, c2_bl, xl, N_NODES, FEAT, FEAT, 0, stream);
    launch_gemm(h, c2_Wr, c2_br, xr, N_NODES, FEAT, FEAT, 0, stream);
    k_gat<4, 1><<<N_NODES / 4, 256, 0, stream>>>(xl, xr, ea, loop_attr, srcArr, elist, rowptr,
                                                 c2_We, c2_att, c2_bias, h);
    // layer 3 (heads=1, no relu)
    launch_gemm(h, c3_Wl, c3_bl, xl, N_NODES, FEAT, FEAT, 0, stream);
    launch_gemm(h, c3_Wr, c3_br, xr, N_NODES, FEAT, FEAT, 0, stream);
    k_gat<1, 0><<<N_NODES / 4, 256, 0, stream>>>(xl, xr, ea, loop_attr, srcArr, elist, rowptr,
                                                 c3_We, c3_att, c3_bias, h);

    // pooling + head
    launch_gemm(h, gate_W1, gate_b1, ghid, N_NODES, 128, FEAT, 1, stream);
    k_gate_score<<<N_NODES / 4, 256, 0, stream>>>(ghid, gate_W2, gate_b2, gate);
    k_pool<<<BATCH, 256, 0, stream>>>(gate, h, batch, gpool);
    k_reg<<<BATCH, 128, 0, stream>>>(gpool, reg_W1, reg_b1, reg_W2, reg_b2, (float*)d_out);
}

// Round 2
// 1725.707 us; speedup vs baseline: 1.3013x; 1.3013x over previous
//
#include <hip/hip_runtime.h>
#include <math.h>

constexpr int N_NODES = 40000;
constexpr int N_EDGES = 500000;
constexpr int ETOT    = N_EDGES + N_NODES;
constexpr int IN_DIM  = 128;
constexpr int ED_DIM  = 16;
constexpr int FEAT    = 256;   // H*C for every layer
constexpr int BATCH   = 128;
constexpr float NEG   = 0.2f;
constexpr int NCHUNK  = (N_NODES + 255) / 256;  // 157

// ---------------- CSR build (by dst, incl. self loops) ----------------
__global__ __launch_bounds__(256) void k_deg(const int* __restrict__ dst, int* __restrict__ deg)
{
    int e = blockIdx.x * 256 + threadIdx.x;
    if (e >= ETOT) return;
    int v = e < N_EDGES ? dst[e] : e - N_EDGES;
    atomicAdd(&deg[v], 1);
}

__global__ __launch_bounds__(256) void k_scan1(const int* __restrict__ deg, int* __restrict__ bsum)
{
    __shared__ int s[256];
    int t = threadIdx.x;
    int idx = blockIdx.x * 256 + t;
    s[t] = idx < N_NODES ? deg[idx] : 0;
    __syncthreads();
    for (int st = 128; st; st >>= 1) { if (t < st) s[t] += s[t + st]; __syncthreads(); }
    if (t == 0) bsum[blockIdx.x] = s[0];
}

__global__ __launch_bounds__(256) void k_scan2(const int* __restrict__ bsum,
    int* __restrict__ boff, int* __restrict__ rowptr)
{
    __shared__ int s[256];
    int t = threadIdx.x;
    int v = t < NCHUNK ? bsum[t] : 0;
    s[t] = v;
    __syncthreads();
    for (int off = 1; off < 256; off <<= 1) {
        int x = (t >= off) ? s[t - off] : 0;
        __syncthreads();
        s[t] += x;
        __syncthreads();
    }
    if (t < NCHUNK) boff[t] = s[t] - v;
    if (t == 0) rowptr[N_NODES] = ETOT;
}

__global__ __launch_bounds__(256) void k_scan3(const int* __restrict__ deg,
    const int* __restrict__ boff, int* __restrict__ rowptr)
{
    __shared__ int s[256];
    int t = threadIdx.x;
    int idx = blockIdx.x * 256 + t;
    int v = idx < N_NODES ? deg[idx] : 0;
    s[t] = v;
    __syncthreads();
    for (int off = 1; off < 256; off <<= 1) {
        int x = (t >= off) ? s[t - off] : 0;
        __syncthreads();
        s[t] += x;
        __syncthreads();
    }
    if (idx < N_NODES) rowptr[idx] = boff[blockIdx.x] + s[t] - v;
}

__global__ __launch_bounds__(256) void k_fill(const int* __restrict__ dst,
    const int* __restrict__ rowptr, int* __restrict__ fill, int* __restrict__ elist)
{
    int e = blockIdx.x * 256 + threadIdx.x;
    if (e >= ETOT) return;
    int v = e < N_EDGES ? dst[e] : e - N_EDGES;
    int pos = rowptr[v] + atomicAdd(&fill[v], 1);
    elist[pos] = e;
}

// ---------------- self-loop mean edge attr via CSR (no atomics) ----------------
__global__ __launch_bounds__(256) void k_loop_csr(const int* __restrict__ elist,
    const int* __restrict__ rowptr, const float* __restrict__ ea, float* __restrict__ loop_attr)
{
    int t = blockIdx.x * 256 + threadIdx.x;
    if (t >= N_NODES * ED_DIM) return;
    int n = t >> 4, d = t & 15;
    int p0 = rowptr[n], p1 = rowptr[n + 1];
    float s = 0.f; int c = 0;
    for (int p = p0; p < p1; ++p) {
        int e = elist[p];
        if (e < N_EDGES) { s += ea[(size_t)e * ED_DIM + d]; ++c; }
    }
    loop_attr[t] = s / (float)(c > 0 ? c : 1);
}

// ---------------- fp32 tiled GEMM: C[M,N] = A[M,K] @ W[K,N] + bias (+relu) ----------------
__global__ __launch_bounds__(256) void k_gemm(const float* __restrict__ A, const float* __restrict__ W,
    const float* __restrict__ bias, float* __restrict__ C, int M, int N, int K, int act)
{
    __shared__ float As[16][68];   // 68: keeps float4 rows 16B-aligned, 2-way banks (free)
    __shared__ float Ws[16][68];
    int t = threadIdx.x;
    int bm = blockIdx.x * 64, bn = blockIdx.y * 64;
    int tm = (t >> 4) << 2, tn = (t & 15) << 2;
    int am = t >> 2, ak4 = (t & 3) << 2;
    int wk = t >> 4, wn4 = (t & 15) << 2;
    float acc[4][4] = {};
    for (int k0 = 0; k0 < K; k0 += 16) {
        float4 av = *reinterpret_cast<const float4*>(A + (size_t)(bm + am) * K + k0 + ak4);
        float4 wv = *reinterpret_cast<const float4*>(W + (size_t)(wk + k0) * N + bn + wn4);
        As[ak4 + 0][am] = av.x; As[ak4 + 1][am] = av.y; As[ak4 + 2][am] = av.z; As[ak4 + 3][am] = av.w;
        *reinterpret_cast<float4*>(&Ws[wk][wn4]) = wv;
        __syncthreads();
        #pragma unroll
        for (int k = 0; k < 16; ++k) {
            float4 a = *reinterpret_cast<const float4*>(&As[k][tm]);
            float4 b = *reinterpret_cast<const float4*>(&Ws[k][tn]);
            acc[0][0] += a.x * b.x; acc[0][1] += a.x * b.y; acc[0][2] += a.x * b.z; acc[0][3] += a.x * b.w;
            acc[1][0] += a.y * b.x; acc[1][1] += a.y * b.y; acc[1][2] += a.y * b.z; acc[1][3] += a.y * b.w;
            acc[2][0] += a.z * b.x; acc[2][1] += a.z * b.y; acc[2][2] += a.z * b.z; acc[2][3] += a.z * b.w;
            acc[3][0] += a.w * b.x; acc[3][1] += a.w * b.y; acc[3][2] += a.w * b.z; acc[3][3] += a.w * b.w;
        }
        __syncthreads();
    }
    #pragma unroll
    for (int i = 0; i < 4; ++i) {
        float4 v;
        v.x = acc[i][0] + bias[bn + tn + 0];
        v.y = acc[i][1] + bias[bn + tn + 1];
        v.z = acc[i][2] + bias[bn + tn + 2];
        v.w = acc[i][3] + bias[bn + tn + 3];
        if (act) { v.x = fmaxf(v.x, 0.f); v.y = fmaxf(v.y, 0.f); v.z = fmaxf(v.z, 0.f); v.w = fmaxf(v.w, 0.f); }
        *reinterpret_cast<float4*>(C + (size_t)(bm + tm + i) * N + bn + tn) = v;
    }
}

static void launch_gemm(const float* A, const float* W, const float* bias, float* C,
                        int M, int N, int K, int act, hipStream_t stream)
{
    dim3 grid(M / 64, N / 64);
    k_gemm<<<grid, 256, 0, stream>>>(A, W, bias, C, M, N, K, act);
}

// ---------------- fused GATv2: one wave per dst node, quarter-wave head layout ----------------
// channel idx(j) = q*64 + u + 16*j, q = lane>>4 (== head for H=4), u = lane&15.
// We kept in 64 VGPRs per lane; no LDS, no __syncthreads.

#define LOAD_EDGE(S, pp) do {                                                         \
    int e_ = elist[pp];                                                               \
    int real_ = e_ < N_EDGES;                                                         \
    int ec_ = real_ ? e_ : 0;                                                         \
    int sl_ = e_ - N_EDGES;                                                           \
    src##S = real_ ? srcArr[ec_] : sl_;                                               \
    const float* eb_ = real_ ? (ea + (size_t)e_ * ED_DIM)                             \
                             : (loop_attr + (size_t)(real_ ? 0 : sl_) * ED_DIM);      \
    const float4* eb4_ = reinterpret_cast<const float4*>(eb_);                        \
    float4 q0_ = eb4_[0], q1_ = eb4_[1], q2_ = eb4_[2], q3_ = eb4_[3];                \
    ev##S[0]=q0_.x;  ev##S[1]=q0_.y;  ev##S[2]=q0_.z;  ev##S[3]=q0_.w;                \
    ev##S[4]=q1_.x;  ev##S[5]=q1_.y;  ev##S[6]=q1_.z;  ev##S[7]=q1_.w;                \
    ev##S[8]=q2_.x;  ev##S[9]=q2_.y;  ev##S[10]=q2_.z; ev##S[11]=q2_.w;               \
    ev##S[12]=q3_.x; ev##S[13]=q3_.y; ev##S[14]=q3_.z; ev##S[15]=q3_.w;               \
    const float* xp_ = xl + (size_t)src##S * FEAT + base;                             \
    xlv##S[0] = xp_[0]; xlv##S[1] = xp_[16]; xlv##S[2] = xp_[32]; xlv##S[3] = xp_[48];\
} while (0)

#define COMPUTE_EDGE(S) do {                                                          \
    float ef0_ = 0.f, ef1_ = 0.f, ef2_ = 0.f, ef3_ = 0.f;                             \
    _Pragma("unroll")                                                                 \
    for (int d_ = 0; d_ < ED_DIM; ++d_) {                                             \
        float a_ = ev##S[d_];                                                         \
        ef0_ += a_ * weR[d_][0]; ef1_ += a_ * weR[d_][1];                             \
        ef2_ += a_ * weR[d_][2]; ef3_ += a_ * weR[d_][3];                             \
    }                                                                                 \
    float s0_ = xlv##S[0] + xrv[0] + ef0_;                                            \
    float s1_ = xlv##S[1] + xrv[1] + ef1_;                                            \
    float s2_ = xlv##S[2] + xrv[2] + ef2_;                                            \
    float s3_ = xlv##S[3] + xrv[3] + ef3_;                                            \
    s0_ = fmaxf(s0_, 0.f) + NEG * fminf(s0_, 0.f);                                    \
    s1_ = fmaxf(s1_, 0.f) + NEG * fminf(s1_, 0.f);                                    \
    s2_ = fmaxf(s2_, 0.f) + NEG * fminf(s2_, 0.f);                                    \
    s3_ = fmaxf(s3_, 0.f) + NEG * fminf(s3_, 0.f);                                    \
    float l_ = s0_ * attR[0] + s1_ * attR[1] + s2_ * attR[2] + s3_ * attR[3];         \
    l_ += __shfl_xor(l_, 1, 64);                                                      \
    l_ += __shfl_xor(l_, 2, 64);                                                      \
    l_ += __shfl_xor(l_, 4, 64);                                                      \
    l_ += __shfl_xor(l_, 8, 64);                                                      \
    if (H == 1) { l_ += __shfl_xor(l_, 16, 64); l_ += __shfl_xor(l_, 32, 64); }       \
    float nm_ = fmaxf(m, l_);                                                         \
    float sc_ = __expf(m - nm_);                                                      \
    float w_  = __expf(l_ - nm_);                                                     \
    z = z * sc_ + w_;                                                                 \
    m = nm_;                                                                          \
    acc[0] = acc[0] * sc_ + w_ * xlv##S[0];                                           \
    acc[1] = acc[1] * sc_ + w_ * xlv##S[1];                                           \
    acc[2] = acc[2] * sc_ + w_ * xlv##S[2];                                           \
    acc[3] = acc[3] * sc_ + w_ * xlv##S[3];                                           \
} while (0)

template <int H, int RELU>
__global__ __launch_bounds__(256) void k_gat(
    const float* __restrict__ xl, const float* __restrict__ xr,
    const float* __restrict__ ea, const float* __restrict__ loop_attr,
    const int* __restrict__ srcArr, const int* __restrict__ elist, const int* __restrict__ rowptr,
    const float* __restrict__ We, const float* __restrict__ att,
    const float* __restrict__ bias, float* __restrict__ out)
{
    int t = threadIdx.x;
    int lane = t & 63;
    int n = blockIdx.x * 4 + (t >> 6);
    int q = lane >> 4;
    int u = lane & 15;
    int base = q * 64 + u;

    float weR[ED_DIM][4];
    #pragma unroll
    for (int d = 0; d < ED_DIM; ++d) {
        #pragma unroll
        for (int j = 0; j < 4; ++j) weR[d][j] = We[d * FEAT + base + 16 * j];
    }
    float attR[4], biasR[4], xrv[4];
    #pragma unroll
    for (int j = 0; j < 4; ++j) {
        attR[j]  = att[base + 16 * j];
        biasR[j] = bias[base + 16 * j];
        xrv[j]   = xr[(size_t)n * FEAT + base + 16 * j];
    }

    float m = -INFINITY, z = 0.f;
    float acc[4] = {0.f, 0.f, 0.f, 0.f};

    int p0 = rowptr[n], p1 = rowptr[n + 1];   // p1 > p0 guaranteed (self-loop)

    int srcA, srcB;
    float evA[16], evB[16], xlvA[4], xlvB[4];
    (void)srcA; (void)srcB;

    LOAD_EDGE(A, p0);
    int p = p0;
    while (p < p1) {
        if (p + 1 < p1) LOAD_EDGE(B, p + 1);
        COMPUTE_EDGE(A);
        ++p;
        if (p >= p1) break;
        if (p + 1 < p1) LOAD_EDGE(A, p + 1);
        COMPUTE_EDGE(B);
        ++p;
    }

    float inv = 1.0f / (z + 1e-16f);
    #pragma unroll
    for (int j = 0; j < 4; ++j) {
        float o = acc[j] * inv + biasR[j];
        if (RELU) o = fmaxf(o, 0.f);
        out[(size_t)n * FEAT + base + 16 * j] = o;
    }
}

// ---------------- gate score: gate[n] = ghid[n,:] @ W2 + b2 ----------------
__global__ __launch_bounds__(256) void k_gate_score(const float* __restrict__ ghid,
    const float* __restrict__ W2, const float* __restrict__ b2, float* __restrict__ gate)
{
    int lane = threadIdx.x & 63;
    int n = blockIdx.x * 4 + (threadIdx.x >> 6);
    float v = ghid[(size_t)n * 128 + lane] * W2[lane] + ghid[(size_t)n * 128 + lane + 64] * W2[lane + 64];
    #pragma unroll
    for (int off = 32; off > 0; off >>= 1) v += __shfl_xor(v, off, 64);
    if (lane == 0) gate[n] = v + b2[0];
}

// ---------------- attentional pooling: one block per batch segment ----------------
__device__ __forceinline__ int lbound(const int* a, int n, int v)
{
    int lo = 0, hi = n;
    while (lo < hi) { int mid = (lo + hi) >> 1; if (a[mid] < v) lo = mid + 1; else hi = mid; }
    return lo;
}

__global__ __launch_bounds__(256) void k_pool(const float* __restrict__ gate,
    const float* __restrict__ h, const int* __restrict__ batch, float* __restrict__ g)
{
    int b = blockIdx.x;
    int t = threadIdx.x;
    __shared__ float red[256];
    int start = lbound(batch, N_NODES, b);
    int end   = lbound(batch, N_NODES, b + 1);

    float mx = -INFINITY;
    for (int n = start + t; n < end; n += 256) mx = fmaxf(mx, gate[n]);
    red[t] = mx; __syncthreads();
    for (int s = 128; s; s >>= 1) { if (t < s) red[t] = fmaxf(red[t], red[t + s]); __syncthreads(); }
    float m = red[0];
    __syncthreads();

    float zs = 0.f;
    for (int n = start + t; n < end; n += 256) zs += __expf(gate[n] - m);
    red[t] = zs; __syncthreads();
    for (int s = 128; s; s >>= 1) { if (t < s) red[t] += red[t + s]; __syncthreads(); }
    float z = red[0];

    float gs = 0.f;
    for (int n = start; n < end; ++n) gs += __expf(gate[n] - m) * h[(size_t)n * FEAT + t];
    g[b * FEAT + t] = gs / (z + 1e-16f);
}

// ---------------- regression head: per-batch tiny MLP ----------------
__global__ __launch_bounds__(128) void k_reg(const float* __restrict__ g,
    const float* __restrict__ W1, const float* __restrict__ b1,
    const float* __restrict__ W2, const float* __restrict__ b2, float* __restrict__ out)
{
    int b = blockIdx.x, t = threadIdx.x;
    __shared__ float sg[FEAT];
    sg[t] = g[b * FEAT + t];
    sg[t + 128] = g[b * FEAT + t + 128];
    __syncthreads();
    float hv = b1[t];
    for (int k = 0; k < FEAT; ++k) hv += sg[k] * W1[k * 128 + t];
    hv = fmaxf(hv, 0.f);
    __shared__ float p0s[128], p1s[128];
    p0s[t] = hv * W2[t * 2 + 0];
    p1s[t] = hv * W2[t * 2 + 1];
    __syncthreads();
    for (int s = 64; s; s >>= 1) {
        if (t < s) { p0s[t] += p0s[t + s]; p1s[t] += p1s[t + s]; }
        __syncthreads();
    }
    if (t == 0) { out[b * 2 + 0] = p0s[0] + b2[0]; out[b * 2 + 1] = p1s[0] + b2[1]; }
}

// ---------------- launch ----------------
extern "C" void kernel_launch(void* const* d_in, const int* in_sizes, int n_in,
                              void* d_out, int out_size, void* d_ws, size_t ws_size,
                              hipStream_t stream)
{
    const float* x       = (const float*)d_in[0];
    const int*   ei      = (const int*)d_in[1];   // [2,E]
    const float* ea      = (const float*)d_in[2];
    const int*   batch   = (const int*)d_in[3];
    const float* c1_Wl   = (const float*)d_in[5];
    const float* c1_bl   = (const float*)d_in[6];
    const float* c1_Wr   = (const float*)d_in[7];
    const float* c1_br   = (const float*)d_in[8];
    const float* c1_We   = (const float*)d_in[9];
    const float* c1_att  = (const float*)d_in[10];
    const float* c1_bias = (const float*)d_in[11];
    const float* c2_Wl   = (const float*)d_in[12];
    const float* c2_bl   = (const float*)d_in[13];
    const float* c2_Wr   = (const float*)d_in[14];
    const float* c2_br   = (const float*)d_in[15];
    const float* c2_We   = (const float*)d_in[16];
    const float* c2_att  = (const float*)d_in[17];
    const float* c2_bias = (const float*)d_in[18];
    const float* c3_Wl   = (const float*)d_in[19];
    const float* c3_bl   = (const float*)d_in[20];
    const float* c3_Wr   = (const float*)d_in[21];
    const float* c3_br   = (const float*)d_in[22];
    const float* c3_We   = (const float*)d_in[23];
    const float* c3_att  = (const float*)d_in[24];
    const float* c3_bias = (const float*)d_in[25];
    const float* gate_W1 = (const float*)d_in[26];
    const float* gate_b1 = (const float*)d_in[27];
    const float* gate_W2 = (const float*)d_in[28];
    const float* gate_b2 = (const float*)d_in[29];
    const float* reg_W1  = (const float*)d_in[30];
    const float* reg_b1  = (const float*)d_in[31];
    const float* reg_W2  = (const float*)d_in[32];
    const float* reg_b2  = (const float*)d_in[33];

    const int* srcArr = ei;            // row 0
    const int* dstArr = ei + N_EDGES;  // row 1

    float* ws = (float*)d_ws;
    size_t off = 0;
    auto alloc = [&](size_t nf) { float* p = ws + off; off += (nf + 63) & ~(size_t)63; return p; };
    float* xl        = alloc((size_t)N_NODES * FEAT);
    float* xr        = alloc((size_t)N_NODES * FEAT);
    float* h         = alloc((size_t)N_NODES * FEAT);
    float* loop_attr = alloc((size_t)N_NODES * ED_DIM);
    float* gpool     = alloc((size_t)BATCH * FEAT);
    int* ibase  = (int*)(ws + off);
    int* deg    = ibase;
    int* fill   = ibase + N_NODES;
    int* rowptr = ibase + 2 * N_NODES;            // N+1 ints
    int* bsum   = ibase + 3 * N_NODES + 64;
    int* boff   = bsum + 256;
    int* elist  = boff + 256;

    // aliases at disjoint lifetimes
    float* ghid = xl;                       // after L3 gat, xl is dead
    float* gate = xr;

    hipMemsetAsync(deg, 0, (size_t)2 * N_NODES * sizeof(int), stream);

    // CSR build, then self-loop mean attrs from CSR
    k_deg<<<(ETOT + 255) / 256, 256, 0, stream>>>(dstArr, deg);
    k_scan1<<<NCHUNK, 256, 0, stream>>>(deg, bsum);
    k_scan2<<<1, 256, 0, stream>>>(bsum, boff, rowptr);
    k_scan3<<<NCHUNK, 256, 0, stream>>>(deg, boff, rowptr);
    k_fill<<<(ETOT + 255) / 256, 256, 0, stream>>>(dstArr, rowptr, fill, elist);
    k_loop_csr<<<(N_NODES * ED_DIM + 255) / 256, 256, 0, stream>>>(elist, rowptr, ea, loop_attr);

    // layer 1 (in: x [N,128])
    launch_gemm(x, c1_Wl, c1_bl, xl, N_NODES, FEAT, IN_DIM, 0, stream);
    launch_gemm(x, c1_Wr, c1_br, xr, N_NODES, FEAT, IN_DIM, 0, stream);
    k_gat<4, 1><<<N_NODES / 4, 256, 0, stream>>>(xl, xr, ea, loop_attr, srcArr, elist, rowptr,
                                                 c1_We, c1_att, c1_bias, h);
    // layer 2
    launch_gemm(h, c2_Wl, c2_bl, xl, N_NODES, FEAT, FEAT, 0, stream);
    launch_gemm(h, c2_Wr, c2_br, xr, N_NODES, FEAT, FEAT, 0, stream);
    k_gat<4, 1><<<N_NODES / 4, 256, 0, stream>>>(xl, xr, ea, loop_attr, srcArr, elist, rowptr,
                                                 c2_We, c2_att, c2_bias, h);
    // layer 3 (heads=1, no relu)
    launch_gemm(h, c3_Wl, c3_bl, xl, N_NODES, FEAT, FEAT, 0, stream);
    launch_gemm(h, c3_Wr, c3_br, xr, N_NODES, FEAT, FEAT, 0, stream);
    k_gat<1, 0><<<N_NODES / 4, 256, 0, stream>>>(xl, xr, ea, loop_attr, srcArr, elist, rowptr,
                                                 c3_We, c3_att, c3_bias, h);

    // pooling + head
    launch_gemm(h, gate_W1, gate_b1, ghid, N_NODES, 128, FEAT, 1, stream);
    k_gate_score<<<N_NODES / 4, 256, 0, stream>>>(ghid, gate_W2, gate_b2, gate);
    k_pool<<<BATCH, 256, 0, stream>>>(gate, h, batch, gpool);
    k_reg<<<BATCH, 128, 0, stream>>>(gpool, reg_W1, reg_b1, reg_W2, reg_b2, (float*)d_out);
}

// Round 3
// 1227.921 us; speedup vs baseline: 1.8289x; 1.4054x over previous
//
#include <hip/hip_runtime.h>
#include <math.h>

constexpr int N_NODES = 40000;
constexpr int N_EDGES = 500000;
constexpr int ETOT    = N_EDGES + N_NODES;
constexpr int IN_DIM  = 128;
constexpr int ED_DIM  = 16;
constexpr int FEAT    = 256;   // H*C for every layer
constexpr int BATCH   = 128;
constexpr float NEG   = 0.2f;
constexpr int NCHUNK  = (N_NODES + 255) / 256;  // 157

// ---------------- CSR build (by dst, incl. self loops) ----------------
__global__ __launch_bounds__(256) void k_deg(const int* __restrict__ dst, int* __restrict__ deg)
{
    int e = blockIdx.x * 256 + threadIdx.x;
    if (e >= ETOT) return;
    int v = e < N_EDGES ? dst[e] : e - N_EDGES;
    atomicAdd(&deg[v], 1);
}

__global__ __launch_bounds__(256) void k_scan1(const int* __restrict__ deg, int* __restrict__ bsum)
{
    __shared__ int s[256];
    int t = threadIdx.x;
    int idx = blockIdx.x * 256 + t;
    s[t] = idx < N_NODES ? deg[idx] : 0;
    __syncthreads();
    for (int st = 128; st; st >>= 1) { if (t < st) s[t] += s[t + st]; __syncthreads(); }
    if (t == 0) bsum[blockIdx.x] = s[0];
}

__global__ __launch_bounds__(256) void k_scan2(const int* __restrict__ bsum,
    int* __restrict__ boff, int* __restrict__ rowptr)
{
    __shared__ int s[256];
    int t = threadIdx.x;
    int v = t < NCHUNK ? bsum[t] : 0;
    s[t] = v;
    __syncthreads();
    for (int off = 1; off < 256; off <<= 1) {
        int x = (t >= off) ? s[t - off] : 0;
        __syncthreads();
        s[t] += x;
        __syncthreads();
    }
    if (t < NCHUNK) boff[t] = s[t] - v;
    if (t == 0) rowptr[N_NODES] = ETOT;
}

__global__ __launch_bounds__(256) void k_scan3(const int* __restrict__ deg,
    const int* __restrict__ boff, int* __restrict__ rowptr)
{
    __shared__ int s[256];
    int t = threadIdx.x;
    int idx = blockIdx.x * 256 + t;
    int v = idx < N_NODES ? deg[idx] : 0;
    s[t] = v;
    __syncthreads();
    for (int off = 1; off < 256; off <<= 1) {
        int x = (t >= off) ? s[t - off] : 0;
        __syncthreads();
        s[t] += x;
        __syncthreads();
    }
    if (idx < N_NODES) rowptr[idx] = boff[blockIdx.x] + s[t] - v;
}

__global__ __launch_bounds__(256) void k_fill(const int* __restrict__ dst,
    const int* __restrict__ rowptr, int* __restrict__ fill, int* __restrict__ elist)
{
    int e = blockIdx.x * 256 + threadIdx.x;
    if (e >= ETOT) return;
    int v = e < N_EDGES ? dst[e] : e - N_EDGES;
    int pos = rowptr[v] + atomicAdd(&fill[v], 1);
    elist[pos] = e;
}

// ---------------- self-loop mean edge attr via CSR (no atomics) ----------------
__global__ __launch_bounds__(256) void k_loop_csr(const int* __restrict__ elist,
    const int* __restrict__ rowptr, const float* __restrict__ ea, float* __restrict__ loop_attr)
{
    int t = blockIdx.x * 256 + threadIdx.x;
    if (t >= N_NODES * ED_DIM) return;
    int n = t >> 4, d = t & 15;
    int p0 = rowptr[n], p1 = rowptr[n + 1];
    float s = 0.f; int c = 0;
    for (int p = p0; p < p1; ++p) {
        int e = elist[p];
        if (e < N_EDGES) { s += ea[(size_t)e * ED_DIM + d]; ++c; }
    }
    loop_attr[t] = s / (float)(c > 0 ? c : 1);
}

// ---------------- fp32 GEMM: C[M,N] = A[M,K] @ W[K,N] + bias (+relu) ----------------
// 64(M) x 128(N) tile, BK=16, 256 threads, 4x8 acc/thread.
__global__ __launch_bounds__(256) void k_gemm(const float* __restrict__ A, const float* __restrict__ W,
    const float* __restrict__ bias, float* __restrict__ C, int M, int N, int K, int act)
{
    __shared__ float As[16][68];    // [k][m], padded: 272B rows keep 16B align, 2-way banks free
    __shared__ float Bs[16][132];   // [k][n], 528B rows
    int t = threadIdx.x;
    int bm = blockIdx.x * 64, bn = blockIdx.y * 128;
    int arow = t >> 2, akc = (t & 3) << 2;      // A: 64 rows x 16 k
    int bkr = t >> 4, bnc = (t & 15) << 3;      // B: 16 k x 128 n
    int tmr = (t >> 4) << 2, tnc = (t & 15) << 3;
    float acc[4][8] = {};
    for (int k0 = 0; k0 < K; k0 += 16) {
        float4 av  = *(const float4*)(A + (size_t)(bm + arow) * K + k0 + akc);
        float4 bv0 = *(const float4*)(W + (size_t)(k0 + bkr) * N + bn + bnc);
        float4 bv1 = *(const float4*)(W + (size_t)(k0 + bkr) * N + bn + bnc + 4);
        As[akc + 0][arow] = av.x; As[akc + 1][arow] = av.y;
        As[akc + 2][arow] = av.z; As[akc + 3][arow] = av.w;
        *(float4*)&Bs[bkr][bnc]     = bv0;
        *(float4*)&Bs[bkr][bnc + 4] = bv1;
        __syncthreads();
        #pragma unroll
        for (int k = 0; k < 16; ++k) {
            float4 a  = *(const float4*)&As[k][tmr];
            float4 b0 = *(const float4*)&Bs[k][tnc];
            float4 b1 = *(const float4*)&Bs[k][tnc + 4];
            float am[4] = {a.x, a.y, a.z, a.w};
            float bnv[8] = {b0.x, b0.y, b0.z, b0.w, b1.x, b1.y, b1.z, b1.w};
            #pragma unroll
            for (int i = 0; i < 4; ++i)
                #pragma unroll
                for (int j = 0; j < 8; ++j)
                    acc[i][j] = fmaf(am[i], bnv[j], acc[i][j]);
        }
        __syncthreads();
    }
    float bb[8];
    #pragma unroll
    for (int j = 0; j < 8; ++j) bb[j] = bias[bn + tnc + j];
    #pragma unroll
    for (int i = 0; i < 4; ++i) {
        float4 o0, o1;
        o0.x = acc[i][0] + bb[0]; o0.y = acc[i][1] + bb[1];
        o0.z = acc[i][2] + bb[2]; o0.w = acc[i][3] + bb[3];
        o1.x = acc[i][4] + bb[4]; o1.y = acc[i][5] + bb[5];
        o1.z = acc[i][6] + bb[6]; o1.w = acc[i][7] + bb[7];
        if (act) {
            o0.x = fmaxf(o0.x, 0.f); o0.y = fmaxf(o0.y, 0.f); o0.z = fmaxf(o0.z, 0.f); o0.w = fmaxf(o0.w, 0.f);
            o1.x = fmaxf(o1.x, 0.f); o1.y = fmaxf(o1.y, 0.f); o1.z = fmaxf(o1.z, 0.f); o1.w = fmaxf(o1.w, 0.f);
        }
        *(float4*)(C + (size_t)(bm + tmr + i) * N + bn + tnc)     = o0;
        *(float4*)(C + (size_t)(bm + tmr + i) * N + bn + tnc + 4) = o1;
    }
}

static void launch_gemm(const float* A, const float* W, const float* bias, float* C,
                        int M, int N, int K, int act, hipStream_t stream)
{
    dim3 grid(M / 64, N / 128);
    k_gemm<<<grid, 256, 0, stream>>>(A, W, bias, C, M, N, K, act);
}

// ---------------- fused GATv2: one wave per dst node, quarter-wave head layout ----------------
// channel idx(j) = q*64 + u + 16*j, q = lane>>4 (== head for H=4), u = lane&15.
// weR (We fragment, 64 regs) forced register-resident via __launch_bounds__(256,3).
// Depth-3 pipeline: iter p loads e[p+3], src[p+2], (ea,xl)[p+1], computes edge p.

#define RESOLVE_SRC(s) do {                                                           \
    int e_ = eS[s];                                                                   \
    int real_ = e_ < N_EDGES;                                                         \
    srcS[s] = real_ ? srcArr[real_ ? e_ : 0] : (e_ - N_EDGES);                        \
} while (0)

#define XELOAD(s) do {                                                                \
    int e_ = eS[s];                                                                   \
    int real_ = e_ < N_EDGES;                                                         \
    const float4* eb4_ = reinterpret_cast<const float4*>(                             \
        real_ ? ea + (size_t)e_ * ED_DIM                                              \
              : loop_attr + (size_t)(e_ - N_EDGES) * ED_DIM);                         \
    evS[s][0] = eb4_[0]; evS[s][1] = eb4_[1];                                         \
    evS[s][2] = eb4_[2]; evS[s][3] = eb4_[3];                                         \
    const float* xp_ = xl + (size_t)srcS[s] * FEAT + base;                            \
    xlvS[s][0] = xp_[0]; xlvS[s][1] = xp_[16];                                        \
    xlvS[s][2] = xp_[32]; xlvS[s][3] = xp_[48];                                       \
} while (0)

#define COMPUTE(s) do {                                                               \
    float ef0_ = 0.f, ef1_ = 0.f, ef2_ = 0.f, ef3_ = 0.f;                             \
    const float* ed_ = (const float*)evS[s];                                          \
    _Pragma("unroll")                                                                 \
    for (int d_ = 0; d_ < ED_DIM; ++d_) {                                             \
        float a_ = ed_[d_];                                                           \
        ef0_ = fmaf(a_, weR[d_][0], ef0_); ef1_ = fmaf(a_, weR[d_][1], ef1_);         \
        ef2_ = fmaf(a_, weR[d_][2], ef2_); ef3_ = fmaf(a_, weR[d_][3], ef3_);         \
    }                                                                                 \
    float s0_ = xlvS[s][0] + xrv[0] + ef0_;                                           \
    float s1_ = xlvS[s][1] + xrv[1] + ef1_;                                           \
    float s2_ = xlvS[s][2] + xrv[2] + ef2_;                                           \
    float s3_ = xlvS[s][3] + xrv[3] + ef3_;                                           \
    s0_ = fmaxf(s0_, 0.f) + NEG * fminf(s0_, 0.f);                                    \
    s1_ = fmaxf(s1_, 0.f) + NEG * fminf(s1_, 0.f);                                    \
    s2_ = fmaxf(s2_, 0.f) + NEG * fminf(s2_, 0.f);                                    \
    s3_ = fmaxf(s3_, 0.f) + NEG * fminf(s3_, 0.f);                                    \
    float l_ = fmaf(s0_, attR[0], fmaf(s1_, attR[1], fmaf(s2_, attR[2], s3_ * attR[3])));\
    l_ += __shfl_xor(l_, 1, 64);                                                      \
    l_ += __shfl_xor(l_, 2, 64);                                                      \
    l_ += __shfl_xor(l_, 4, 64);                                                      \
    l_ += __shfl_xor(l_, 8, 64);                                                      \
    if (H == 1) { l_ += __shfl_xor(l_, 16, 64); l_ += __shfl_xor(l_, 32, 64); }       \
    float nm_ = fmaxf(m, l_);                                                         \
    float sc_ = __expf(m - nm_);                                                      \
    float w_  = __expf(l_ - nm_);                                                     \
    z = fmaf(z, sc_, w_);                                                             \
    m = nm_;                                                                          \
    acc[0] = fmaf(acc[0], sc_, w_ * xlvS[s][0]);                                      \
    acc[1] = fmaf(acc[1], sc_, w_ * xlvS[s][1]);                                      \
    acc[2] = fmaf(acc[2], sc_, w_ * xlvS[s][2]);                                      \
    acc[3] = fmaf(acc[3], sc_, w_ * xlvS[s][3]);                                      \
} while (0)

#define STEP(i0, i1, i2) do {                                                         \
    int pn_ = p + 3; pn_ = pn_ > pe ? pe : pn_;                                       \
    eS[i0] = elist[pn_];                                                              \
    RESOLVE_SRC(i2);                                                                  \
    XELOAD(i1);                                                                       \
    COMPUTE(i0);                                                                      \
} while (0)

template <int H, int RELU>
__global__ __launch_bounds__(256, 3) void k_gat(
    const float* __restrict__ xl, const float* __restrict__ xr,
    const float* __restrict__ ea, const float* __restrict__ loop_attr,
    const int* __restrict__ srcArr, const int* __restrict__ elist, const int* __restrict__ rowptr,
    const float* __restrict__ We, const float* __restrict__ att,
    const float* __restrict__ bias, float* __restrict__ out)
{
    int t = threadIdx.x;
    int lane = t & 63;
    int n = __builtin_amdgcn_readfirstlane(blockIdx.x * 4 + (t >> 6));
    int q = lane >> 4;
    int u = lane & 15;
    int base = q * 64 + u;

    float weR[ED_DIM][4];
    #pragma unroll
    for (int d = 0; d < ED_DIM; ++d) {
        #pragma unroll
        for (int j = 0; j < 4; ++j) weR[d][j] = We[d * FEAT + base + 16 * j];
    }
    float attR[4], xrv[4];
    #pragma unroll
    for (int j = 0; j < 4; ++j) {
        attR[j] = att[base + 16 * j];
        xrv[j]  = xr[(size_t)n * FEAT + base + 16 * j];
    }

    float m = -INFINITY, z = 0.f;
    float acc[4] = {0.f, 0.f, 0.f, 0.f};

    int p0 = rowptr[n], p1 = rowptr[n + 1];   // p1 > p0 guaranteed (self-loop)
    int pe = p1 - 1;

    int eS[3], srcS[3];
    float4 evS[3][4];
    float  xlvS[3][4];

    eS[0] = elist[p0];
    { int p1c = p0 + 1 > pe ? pe : p0 + 1; eS[1] = elist[p1c]; }
    { int p2c = p0 + 2 > pe ? pe : p0 + 2; eS[2] = elist[p2c]; }
    RESOLVE_SRC(0);
    RESOLVE_SRC(1);
    XELOAD(0);

    int p = p0;
    while (true) {
        STEP(0, 1, 2); if (++p >= p1) break;
        STEP(1, 2, 0); if (++p >= p1) break;
        STEP(2, 0, 1); if (++p >= p1) break;
    }

    float inv = 1.0f / (z + 1e-16f);
    #pragma unroll
    for (int j = 0; j < 4; ++j) {
        float o = fmaf(acc[j], inv, bias[base + 16 * j]);
        if (RELU) o = fmaxf(o, 0.f);
        out[(size_t)n * FEAT + base + 16 * j] = o;
    }
}

// ---------------- gate score: gate[n] = ghid[n,:] @ W2 + b2 ----------------
__global__ __launch_bounds__(256) void k_gate_score(const float* __restrict__ ghid,
    const float* __restrict__ W2, const float* __restrict__ b2, float* __restrict__ gate)
{
    int lane = threadIdx.x & 63;
    int n = blockIdx.x * 4 + (threadIdx.x >> 6);
    float v = ghid[(size_t)n * 128 + lane] * W2[lane] + ghid[(size_t)n * 128 + lane + 64] * W2[lane + 64];
    #pragma unroll
    for (int off = 32; off > 0; off >>= 1) v += __shfl_xor(v, off, 64);
    if (lane == 0) gate[n] = v + b2[0];
}

// ---------------- attentional pooling: one block per batch segment ----------------
__device__ __forceinline__ int lbound(const int* a, int n, int v)
{
    int lo = 0, hi = n;
    while (lo < hi) { int mid = (lo + hi) >> 1; if (a[mid] < v) lo = mid + 1; else hi = mid; }
    return lo;
}

__global__ __launch_bounds__(256) void k_pool(const float* __restrict__ gate,
    const float* __restrict__ h, const int* __restrict__ batch, float* __restrict__ g)
{
    int b = blockIdx.x;
    int t = threadIdx.x;
    __shared__ float red[256];
    int start = lbound(batch, N_NODES, b);
    int end   = lbound(batch, N_NODES, b + 1);

    float mx = -INFINITY;
    for (int n = start + t; n < end; n += 256) mx = fmaxf(mx, gate[n]);
    red[t] = mx; __syncthreads();
    for (int s = 128; s; s >>= 1) { if (t < s) red[t] = fmaxf(red[t], red[t + s]); __syncthreads(); }
    float m = red[0];
    __syncthreads();

    float zs = 0.f;
    for (int n = start + t; n < end; n += 256) zs += __expf(gate[n] - m);
    red[t] = zs; __syncthreads();
    for (int s = 128; s; s >>= 1) { if (t < s) red[t] += red[t + s]; __syncthreads(); }
    float z = red[0];

    float gs = 0.f;
    for (int n = start; n < end; ++n) gs += __expf(gate[n] - m) * h[(size_t)n * FEAT + t];
    g[b * FEAT + t] = gs / (z + 1e-16f);
}

// ---------------- regression head: per-batch tiny MLP ----------------
__global__ __launch_bounds__(128) void k_reg(const float* __restrict__ g,
    const float* __restrict__ W1, const float* __restrict__ b1,
    const float* __restrict__ W2, const float* __restrict__ b2, float* __restrict__ out)
{
    int b = blockIdx.x, t = threadIdx.x;
    __shared__ float sg[FEAT];
    sg[t] = g[b * FEAT + t];
    sg[t + 128] = g[b * FEAT + t + 128];
    __syncthreads();
    float hv = b1[t];
    for (int k = 0; k < FEAT; ++k) hv += sg[k] * W1[k * 128 + t];
    hv = fmaxf(hv, 0.f);
    __shared__ float p0s[128], p1s[128];
    p0s[t] = hv * W2[t * 2 + 0];
    p1s[t] = hv * W2[t * 2 + 1];
    __syncthreads();
    for (int s = 64; s; s >>= 1) {
        if (t < s) { p0s[t] += p0s[t + s]; p1s[t] += p1s[t + s]; }
        __syncthreads();
    }
    if (t == 0) { out[b * 2 + 0] = p0s[0] + b2[0]; out[b * 2 + 1] = p1s[0] + b2[1]; }
}

// ---------------- launch ----------------
extern "C" void kernel_launch(void* const* d_in, const int* in_sizes, int n_in,
                              void* d_out, int out_size, void* d_ws, size_t ws_size,
                              hipStream_t stream)
{
    const float* x       = (const float*)d_in[0];
    const int*   ei      = (const int*)d_in[1];   // [2,E]
    const float* ea      = (const float*)d_in[2];
    const int*   batch   = (const int*)d_in[3];
    const float* c1_Wl   = (const float*)d_in[5];
    const float* c1_bl   = (const float*)d_in[6];
    const float* c1_Wr   = (const float*)d_in[7];
    const float* c1_br   = (const float*)d_in[8];
    const float* c1_We   = (const float*)d_in[9];
    const float* c1_att  = (const float*)d_in[10];
    const float* c1_bias = (const float*)d_in[11];
    const float* c2_Wl   = (const float*)d_in[12];
    const float* c2_bl   = (const float*)d_in[13];
    const float* c2_Wr   = (const float*)d_in[14];
    const float* c2_br   = (const float*)d_in[15];
    const float* c2_We   = (const float*)d_in[16];
    const float* c2_att  = (const float*)d_in[17];
    const float* c2_bias = (const float*)d_in[18];
    const float* c3_Wl   = (const float*)d_in[19];
    const float* c3_bl   = (const float*)d_in[20];
    const float* c3_Wr   = (const float*)d_in[21];
    const float* c3_br   = (const float*)d_in[22];
    const float* c3_We   = (const float*)d_in[23];
    const float* c3_att  = (const float*)d_in[24];
    const float* c3_bias = (const float*)d_in[25];
    const float* gate_W1 = (const float*)d_in[26];
    const float* gate_b1 = (const float*)d_in[27];
    const float* gate_W2 = (const float*)d_in[28];
    const float* gate_b2 = (const float*)d_in[29];
    const float* reg_W1  = (const float*)d_in[30];
    const float* reg_b1  = (const float*)d_in[31];
    const float* reg_W2  = (const float*)d_in[32];
    const float* reg_b2  = (const float*)d_in[33];

    const int* srcArr = ei;            // row 0
    const int* dstArr = ei + N_EDGES;  // row 1

    float* ws = (float*)d_ws;
    size_t off = 0;
    auto alloc = [&](size_t nf) { float* p = ws + off; off += (nf + 63) & ~(size_t)63; return p; };
    float* xl        = alloc((size_t)N_NODES * FEAT);
    float* xr        = alloc((size_t)N_NODES * FEAT);
    float* h         = alloc((size_t)N_NODES * FEAT);
    float* loop_attr = alloc((size_t)N_NODES * ED_DIM);
    float* gpool     = alloc((size_t)BATCH * FEAT);
    int* ibase  = (int*)(ws + off);
    int* deg    = ibase;
    int* fill   = ibase + N_NODES;
    int* rowptr = ibase + 2 * N_NODES;            // N+1 ints
    int* bsum   = ibase + 3 * N_NODES + 64;
    int* boff   = bsum + 256;
    int* elist  = boff + 256;

    // aliases at disjoint lifetimes
    float* ghid = xl;                       // after L3 gat, xl is dead
    float* gate = xr;

    hipMemsetAsync(deg, 0, (size_t)2 * N_NODES * sizeof(int), stream);

    // CSR build, then self-loop mean attrs from CSR
    k_deg<<<(ETOT + 255) / 256, 256, 0, stream>>>(dstArr, deg);
    k_scan1<<<NCHUNK, 256, 0, stream>>>(deg, bsum);
    k_scan2<<<1, 256, 0, stream>>>(bsum, boff, rowptr);
    k_scan3<<<NCHUNK, 256, 0, stream>>>(deg, boff, rowptr);
    k_fill<<<(ETOT + 255) / 256, 256, 0, stream>>>(dstArr, rowptr, fill, elist);
    k_loop_csr<<<(N_NODES * ED_DIM + 255) / 256, 256, 0, stream>>>(elist, rowptr, ea, loop_attr);

    // layer 1 (in: x [N,128])
    launch_gemm(x, c1_Wl, c1_bl, xl, N_NODES, FEAT, IN_DIM, 0, stream);
    launch_gemm(x, c1_Wr, c1_br, xr, N_NODES, FEAT, IN_DIM, 0, stream);
    k_gat<4, 1><<<N_NODES / 4, 256, 0, stream>>>(xl, xr, ea, loop_attr, srcArr, elist, rowptr,
                                                 c1_We, c1_att, c1_bias, h);
    // layer 2
    launch_gemm(h, c2_Wl, c2_bl, xl, N_NODES, FEAT, FEAT, 0, stream);
    launch_gemm(h, c2_Wr, c2_br, xr, N_NODES, FEAT, FEAT, 0, stream);
    k_gat<4, 1><<<N_NODES / 4, 256, 0, stream>>>(xl, xr, ea, loop_attr, srcArr, elist, rowptr,
                                                 c2_We, c2_att, c2_bias, h);
    // layer 3 (heads=1, no relu)
    launch_gemm(h, c3_Wl, c3_bl, xl, N_NODES, FEAT, FEAT, 0, stream);
    launch_gemm(h, c3_Wr, c3_br, xr, N_NODES, FEAT, FEAT, 0, stream);
    k_gat<1, 0><<<N_NODES / 4, 256, 0, stream>>>(xl, xr, ea, loop_attr, srcArr, elist, rowptr,
                                                 c3_We, c3_att, c3_bias, h);

    // pooling + head
    launch_gemm(h, gate_W1, gate_b1, ghid, N_NODES, 128, FEAT, 1, stream);
    k_gate_score<<<N_NODES / 4, 256, 0, stream>>>(ghid, gate_W2, gate_b2, gate);
    k_pool<<<BATCH, 256, 0, stream>>>(gate, h, batch, gpool);
    k_reg<<<BATCH, 128, 0, stream>>>(gpool, reg_W1, reg_b1, reg_W2, reg_b2, (float*)d_out);
}

// Round 4
// 1215.973 us; speedup vs baseline: 1.8469x; 1.0098x over previous
//
#include <hip/hip_runtime.h>
#include <math.h>

constexpr int N_NODES = 40000;
constexpr int N_EDGES = 500000;
constexpr int ETOT    = N_EDGES + N_NODES;
constexpr int IN_DIM  = 128;
constexpr int ED_DIM  = 16;
constexpr int FEAT    = 256;   // H*C for every layer
constexpr int BATCH   = 128;
constexpr float NEG   = 0.2f;
constexpr int NCHUNK  = (N_NODES + 255) / 256;  // 157

// ---------------- CSR build (by dst, incl. self loops) ----------------
__global__ __launch_bounds__(256) void k_deg(const int* __restrict__ dst, int* __restrict__ deg)
{
    int e = blockIdx.x * 256 + threadIdx.x;
    if (e >= ETOT) return;
    int v = e < N_EDGES ? dst[e] : e - N_EDGES;
    atomicAdd(&deg[v], 1);
}

__global__ __launch_bounds__(256) void k_scan1(const int* __restrict__ deg, int* __restrict__ bsum)
{
    __shared__ int s[256];
    int t = threadIdx.x;
    int idx = blockIdx.x * 256 + t;
    s[t] = idx < N_NODES ? deg[idx] : 0;
    __syncthreads();
    for (int st = 128; st; st >>= 1) { if (t < st) s[t] += s[t + st]; __syncthreads(); }
    if (t == 0) bsum[blockIdx.x] = s[0];
}

__global__ __launch_bounds__(256) void k_scan2(const int* __restrict__ bsum,
    int* __restrict__ boff, int* __restrict__ rowptr)
{
    __shared__ int s[256];
    int t = threadIdx.x;
    int v = t < NCHUNK ? bsum[t] : 0;
    s[t] = v;
    __syncthreads();
    for (int off = 1; off < 256; off <<= 1) {
        int x = (t >= off) ? s[t - off] : 0;
        __syncthreads();
        s[t] += x;
        __syncthreads();
    }
    if (t < NCHUNK) boff[t] = s[t] - v;
    if (t == 0) rowptr[N_NODES] = ETOT;
}

__global__ __launch_bounds__(256) void k_scan3(const int* __restrict__ deg,
    const int* __restrict__ boff, int* __restrict__ rowptr)
{
    __shared__ int s[256];
    int t = threadIdx.x;
    int idx = blockIdx.x * 256 + t;
    int v = idx < N_NODES ? deg[idx] : 0;
    s[t] = v;
    __syncthreads();
    for (int off = 1; off < 256; off <<= 1) {
        int x = (t >= off) ? s[t - off] : 0;
        __syncthreads();
        s[t] += x;
        __syncthreads();
    }
    if (idx < N_NODES) rowptr[idx] = boff[blockIdx.x] + s[t] - v;
}

// elist2[pos] = (src, eid): kills the dependent srcArr gather in k_gat
__global__ __launch_bounds__(256) void k_fill(const int* __restrict__ srcA, const int* __restrict__ dst,
    const int* __restrict__ rowptr, int* __restrict__ fill, int2* __restrict__ elist2)
{
    int e = blockIdx.x * 256 + threadIdx.x;
    if (e >= ETOT) return;
    int v = e < N_EDGES ? dst[e]  : e - N_EDGES;
    int s = e < N_EDGES ? srcA[e] : e - N_EDGES;
    int pos = rowptr[v] + atomicAdd(&fill[v], 1);
    elist2[pos] = make_int2(s, e);
}

// ---------------- self-loop mean edge attr via CSR (no atomics) ----------------
__global__ __launch_bounds__(256) void k_loop_csr(const int2* __restrict__ elist2,
    const int* __restrict__ rowptr, const float* __restrict__ ea, float* __restrict__ loop_attr)
{
    int t = blockIdx.x * 256 + threadIdx.x;
    if (t >= N_NODES * ED_DIM) return;
    int n = t >> 4, d = t & 15;
    int p0 = rowptr[n], p1 = rowptr[n + 1];
    float s = 0.f; int c = 0;
    for (int p = p0; p < p1; ++p) {
        int e = elist2[p].y;
        if (e < N_EDGES) { s += ea[(size_t)e * ED_DIM + d]; ++c; }
    }
    loop_attr[t] = s / (float)(c > 0 ? c : 1);
}

// ---------------- fp32 GEMM: C[M,N] = A[M,K] @ W[K,N] + bias (+relu) ----------------
// 128x128 tile, 256 threads, 8x8 acc/thread (n-frag split 4+4, 64 apart -> 2-way banks only).
// M-guarded (clamped loads, guarded stores); K % 16 == 0, N % 128 == 0.
__global__ __launch_bounds__(256) void k_gemm(const float* __restrict__ A, const float* __restrict__ W,
    const float* __restrict__ bias, float* __restrict__ C, int M, int N, int K, int act)
{
    __shared__ float As[16][136];   // [k][m]
    __shared__ float Bs[16][136];   // [k][n]
    int t = threadIdx.x;
    int bm = blockIdx.x * 128, bn = blockIdx.y * 128;
    int tr = t >> 4, tc = t & 15;
    int mr0 = tr * 8, nc0 = tc * 4;

    float acc[8][8] = {};

    for (int k0 = 0; k0 < K; k0 += 16) {
        // stage A: 128 rows x 16 k = 512 float4; thread handles i = t, t+256
        #pragma unroll
        for (int ii = 0; ii < 2; ++ii) {
            int i = t + ii * 256;
            int row = i >> 2, kq = (i & 3) << 2;
            int r = bm + row; r = r < M ? r : M - 1;
            float4 av = *(const float4*)(A + (size_t)r * K + k0 + kq);
            As[kq + 0][row] = av.x; As[kq + 1][row] = av.y;
            As[kq + 2][row] = av.z; As[kq + 3][row] = av.w;
        }
        // stage B: 16 k x 128 n = 512 float4
        #pragma unroll
        for (int ii = 0; ii < 2; ++ii) {
            int i = t + ii * 256;
            int krow = i >> 5, nq = (i & 31) << 2;
            float4 bv = *(const float4*)(W + (size_t)(k0 + krow) * N + bn + nq);
            *(float4*)&Bs[krow][nq] = bv;
        }
        __syncthreads();
        #pragma unroll
        for (int k = 0; k < 16; ++k) {
            float4 a0 = *(const float4*)&As[k][mr0];
            float4 a1 = *(const float4*)&As[k][mr0 + 4];
            float4 b0 = *(const float4*)&Bs[k][nc0];
            float4 b1 = *(const float4*)&Bs[k][64 + nc0];
            float am[8] = {a0.x, a0.y, a0.z, a0.w, a1.x, a1.y, a1.z, a1.w};
            float bv[8] = {b0.x, b0.y, b0.z, b0.w, b1.x, b1.y, b1.z, b1.w};
            #pragma unroll
            for (int i = 0; i < 8; ++i)
                #pragma unroll
                for (int j = 0; j < 8; ++j)
                    acc[i][j] = fmaf(am[i], bv[j], acc[i][j]);
        }
        __syncthreads();
    }

    float bb[8];
    #pragma unroll
    for (int j = 0; j < 4; ++j) { bb[j] = bias[bn + nc0 + j]; bb[j + 4] = bias[bn + 64 + nc0 + j]; }
    #pragma unroll
    for (int i = 0; i < 8; ++i) {
        int row = bm + mr0 + i;
        if (row >= M) break;
        float4 o0, o1;
        o0.x = acc[i][0] + bb[0]; o0.y = acc[i][1] + bb[1];
        o0.z = acc[i][2] + bb[2]; o0.w = acc[i][3] + bb[3];
        o1.x = acc[i][4] + bb[4]; o1.y = acc[i][5] + bb[5];
        o1.z = acc[i][6] + bb[6]; o1.w = acc[i][7] + bb[7];
        if (act) {
            o0.x = fmaxf(o0.x, 0.f); o0.y = fmaxf(o0.y, 0.f); o0.z = fmaxf(o0.z, 0.f); o0.w = fmaxf(o0.w, 0.f);
            o1.x = fmaxf(o1.x, 0.f); o1.y = fmaxf(o1.y, 0.f); o1.z = fmaxf(o1.z, 0.f); o1.w = fmaxf(o1.w, 0.f);
        }
        *(float4*)(C + (size_t)row * N + bn + nc0)      = o0;
        *(float4*)(C + (size_t)row * N + bn + 64 + nc0) = o1;
    }
}

static void launch_gemm(const float* A, const float* W, const float* bias, float* C,
                        int M, int N, int K, int act, hipStream_t stream)
{
    dim3 grid((M + 127) / 128, N / 128);
    k_gemm<<<grid, 256, 0, stream>>>(A, W, bias, C, M, N, K, act);
}

// ---------------- fused GATv2: one wave per dst node, quarter-wave head layout ----------------
// channel idx(j) = q*64 + u + 16*j, q = lane>>4 (== head for H=4), u = lane&15.
// weR pinned into VGPRs via opaque asm; depth-2 pipeline over (ea, xl) with int2 elist.

#define XELOAD(s) do {                                                                \
    int src_ = eS[s].x, e_ = eS[s].y;                                                 \
    const float4* eb4_ = reinterpret_cast<const float4*>(                             \
        (e_ < N_EDGES) ? ea + (size_t)e_ * ED_DIM                                     \
                       : loop_attr + (size_t)src_ * ED_DIM);                          \
    evS[s][0] = eb4_[0]; evS[s][1] = eb4_[1];                                         \
    evS[s][2] = eb4_[2]; evS[s][3] = eb4_[3];                                         \
    const float* xp_ = xl + (size_t)src_ * FEAT + base;                               \
    xlvS[s][0] = xp_[0];  xlvS[s][1] = xp_[16];                                       \
    xlvS[s][2] = xp_[32]; xlvS[s][3] = xp_[48];                                       \
} while (0)

#define COMPUTE(s) do {                                                               \
    float ef0_ = 0.f, ef1_ = 0.f, ef2_ = 0.f, ef3_ = 0.f;                             \
    const float* ed_ = (const float*)evS[s];                                          \
    _Pragma("unroll")                                                                 \
    for (int d_ = 0; d_ < ED_DIM; ++d_) {                                             \
        float a_ = ed_[d_];                                                           \
        ef0_ = fmaf(a_, weR[d_][0], ef0_); ef1_ = fmaf(a_, weR[d_][1], ef1_);         \
        ef2_ = fmaf(a_, weR[d_][2], ef2_); ef3_ = fmaf(a_, weR[d_][3], ef3_);         \
    }                                                                                 \
    float s0_ = xlvS[s][0] + xrv[0] + ef0_;                                           \
    float s1_ = xlvS[s][1] + xrv[1] + ef1_;                                           \
    float s2_ = xlvS[s][2] + xrv[2] + ef2_;                                           \
    float s3_ = xlvS[s][3] + xrv[3] + ef3_;                                           \
    s0_ = fmaxf(s0_, 0.f) + NEG * fminf(s0_, 0.f);                                    \
    s1_ = fmaxf(s1_, 0.f) + NEG * fminf(s1_, 0.f);                                    \
    s2_ = fmaxf(s2_, 0.f) + NEG * fminf(s2_, 0.f);                                    \
    s3_ = fmaxf(s3_, 0.f) + NEG * fminf(s3_, 0.f);                                    \
    float l_ = fmaf(s0_, attR[0], fmaf(s1_, attR[1], fmaf(s2_, attR[2], s3_ * attR[3])));\
    l_ += __shfl_xor(l_, 1, 64);                                                      \
    l_ += __shfl_xor(l_, 2, 64);                                                      \
    l_ += __shfl_xor(l_, 4, 64);                                                      \
    l_ += __shfl_xor(l_, 8, 64);                                                      \
    if (H == 1) { l_ += __shfl_xor(l_, 16, 64); l_ += __shfl_xor(l_, 32, 64); }       \
    float nm_ = fmaxf(m, l_);                                                         \
    float sc_ = __expf(m - nm_);                                                      \
    float w_  = __expf(l_ - nm_);                                                     \
    z = fmaf(z, sc_, w_);                                                             \
    m = nm_;                                                                          \
    acc[0] = fmaf(acc[0], sc_, w_ * xlvS[s][0]);                                      \
    acc[1] = fmaf(acc[1], sc_, w_ * xlvS[s][1]);                                      \
    acc[2] = fmaf(acc[2], sc_, w_ * xlvS[s][2]);                                      \
    acc[3] = fmaf(acc[3], sc_, w_ * xlvS[s][3]);                                      \
} while (0)

template <int H, int RELU>
__global__ __launch_bounds__(256, 3) void k_gat(
    const float* __restrict__ xl, const float* __restrict__ xr,
    const float* __restrict__ ea, const float* __restrict__ loop_attr,
    const int2* __restrict__ elist2, const int* __restrict__ rowptr,
    const float* __restrict__ We, const float* __restrict__ att,
    const float* __restrict__ bias, float* __restrict__ out)
{
    int t = threadIdx.x;
    int lane = t & 63;
    int n = __builtin_amdgcn_readfirstlane(blockIdx.x * 4 + (t >> 6));
    int q = lane >> 4;
    int u = lane & 15;
    int base = q * 64 + u;

    float weR[ED_DIM][4];
    #pragma unroll
    for (int d = 0; d < ED_DIM; ++d) {
        #pragma unroll
        for (int j = 0; j < 4; ++j) weR[d][j] = We[d * FEAT + base + 16 * j];
    }
    // opaque redefine: forces weR into live VGPRs (no remat / re-load in the loop)
    #pragma unroll
    for (int d = 0; d < ED_DIM; ++d) {
        #pragma unroll
        for (int j = 0; j < 4; ++j) asm volatile("" : "+v"(weR[d][j]));
    }

    float attR[4], xrv[4];
    #pragma unroll
    for (int j = 0; j < 4; ++j) {
        attR[j] = att[base + 16 * j];
        xrv[j]  = xr[(size_t)n * FEAT + base + 16 * j];
    }

    float m = -INFINITY, z = 0.f;
    float acc[4] = {0.f, 0.f, 0.f, 0.f};

    int p0 = rowptr[n], p1 = rowptr[n + 1];   // p1 > p0 guaranteed (self-loop)
    int pe = p1 - 1;

    int2   eS[2];
    float4 evS[2][4];
    float  xlvS[2][4];

    eS[0] = elist2[p0];
    { int pc = p0 + 1 > pe ? pe : p0 + 1; eS[1] = elist2[pc]; }
    XELOAD(0);

    int p = p0;
    while (true) {
        // computing edge p from slot0; slot1 holds entry p+1
        XELOAD(1);
        { int pn = p + 2 > pe ? pe : p + 2; eS[0] = elist2[pn]; }
        COMPUTE(0);
        if (++p >= p1) break;
        XELOAD(0);
        { int pn = p + 2 > pe ? pe : p + 2; eS[1] = elist2[pn]; }
        COMPUTE(1);
        if (++p >= p1) break;
    }

    float inv = 1.0f / (z + 1e-16f);
    #pragma unroll
    for (int j = 0; j < 4; ++j) {
        float o = fmaf(acc[j], inv, bias[base + 16 * j]);
        if (RELU) o = fmaxf(o, 0.f);
        out[(size_t)n * FEAT + base + 16 * j] = o;
    }
}

// ---------------- gate score: gate[n] = ghid[n,:] @ W2 + b2 ----------------
__global__ __launch_bounds__(256) void k_gate_score(const float* __restrict__ ghid,
    const float* __restrict__ W2, const float* __restrict__ b2, float* __restrict__ gate)
{
    int lane = threadIdx.x & 63;
    int n = blockIdx.x * 4 + (threadIdx.x >> 6);
    float v = ghid[(size_t)n * 128 + lane] * W2[lane] + ghid[(size_t)n * 128 + lane + 64] * W2[lane + 64];
    #pragma unroll
    for (int off = 32; off > 0; off >>= 1) v += __shfl_xor(v, off, 64);
    if (lane == 0) gate[n] = v + b2[0];
}

// ---------------- attentional pooling: one block per batch segment ----------------
__device__ __forceinline__ int lbound(const int* a, int n, int v)
{
    int lo = 0, hi = n;
    while (lo < hi) { int mid = (lo + hi) >> 1; if (a[mid] < v) lo = mid + 1; else hi = mid; }
    return lo;
}

__global__ __launch_bounds__(256) void k_pool(const float* __restrict__ gate,
    const float* __restrict__ h, const int* __restrict__ batch, float* __restrict__ g)
{
    int b = blockIdx.x;
    int t = threadIdx.x;
    __shared__ float red[256];
    int start = lbound(batch, N_NODES, b);
    int end   = lbound(batch, N_NODES, b + 1);

    float mx = -INFINITY;
    for (int n = start + t; n < end; n += 256) mx = fmaxf(mx, gate[n]);
    red[t] = mx; __syncthreads();
    for (int s = 128; s; s >>= 1) { if (t < s) red[t] = fmaxf(red[t], red[t + s]); __syncthreads(); }
    float m = red[0];
    __syncthreads();

    float zs = 0.f;
    for (int n = start + t; n < end; n += 256) zs += __expf(gate[n] - m);
    red[t] = zs; __syncthreads();
    for (int s = 128; s; s >>= 1) { if (t < s) red[t] += red[t + s]; __syncthreads(); }
    float z = red[0];

    float gs = 0.f;
    for (int n = start; n < end; ++n) gs += __expf(gate[n] - m) * h[(size_t)n * FEAT + t];
    g[b * FEAT + t] = gs / (z + 1e-16f);
}

// ---------------- regression head: per-batch tiny MLP ----------------
__global__ __launch_bounds__(128) void k_reg(const float* __restrict__ g,
    const float* __restrict__ W1, const float* __restrict__ b1,
    const float* __restrict__ W2, const float* __restrict__ b2, float* __restrict__ out)
{
    int b = blockIdx.x, t = threadIdx.x;
    __shared__ float sg[FEAT];
    sg[t] = g[b * FEAT + t];
    sg[t + 128] = g[b * FEAT + t + 128];
    __syncthreads();
    float hv = b1[t];
    for (int k = 0; k < FEAT; ++k) hv += sg[k] * W1[k * 128 + t];
    hv = fmaxf(hv, 0.f);
    __shared__ float p0s[128], p1s[128];
    p0s[t] = hv * W2[t * 2 + 0];
    p1s[t] = hv * W2[t * 2 + 1];
    __syncthreads();
    for (int s = 64; s; s >>= 1) {
        if (t < s) { p0s[t] += p0s[t + s]; p1s[t] += p1s[t + s]; }
        __syncthreads();
    }
    if (t == 0) { out[b * 2 + 0] = p0s[0] + b2[0]; out[b * 2 + 1] = p1s[0] + b2[1]; }
}

// ---------------- launch ----------------
extern "C" void kernel_launch(void* const* d_in, const int* in_sizes, int n_in,
                              void* d_out, int out_size, void* d_ws, size_t ws_size,
                              hipStream_t stream)
{
    const float* x       = (const float*)d_in[0];
    const int*   ei      = (const int*)d_in[1];   // [2,E]
    const float* ea      = (const float*)d_in[2];
    const int*   batch   = (const int*)d_in[3];
    const float* c1_Wl   = (const float*)d_in[5];
    const float* c1_bl   = (const float*)d_in[6];
    const float* c1_Wr   = (const float*)d_in[7];
    const float* c1_br   = (const float*)d_in[8];
    const float* c1_We   = (const float*)d_in[9];
    const float* c1_att  = (const float*)d_in[10];
    const float* c1_bias = (const float*)d_in[11];
    const float* c2_Wl   = (const float*)d_in[12];
    const float* c2_bl   = (const float*)d_in[13];
    const float* c2_Wr   = (const float*)d_in[14];
    const float* c2_br   = (const float*)d_in[15];
    const float* c2_We   = (const float*)d_in[16];
    const float* c2_att  = (const float*)d_in[17];
    const float* c2_bias = (const float*)d_in[18];
    const float* c3_Wl   = (const float*)d_in[19];
    const float* c3_bl   = (const float*)d_in[20];
    const float* c3_Wr   = (const float*)d_in[21];
    const float* c3_br   = (const float*)d_in[22];
    const float* c3_We   = (const float*)d_in[23];
    const float* c3_att  = (const float*)d_in[24];
    const float* c3_bias = (const float*)d_in[25];
    const float* gate_W1 = (const float*)d_in[26];
    const float* gate_b1 = (const float*)d_in[27];
    const float* gate_W2 = (const float*)d_in[28];
    const float* gate_b2 = (const float*)d_in[29];
    const float* reg_W1  = (const float*)d_in[30];
    const float* reg_b1  = (const float*)d_in[31];
    const float* reg_W2  = (const float*)d_in[32];
    const float* reg_b2  = (const float*)d_in[33];

    const int* srcArr = ei;            // row 0
    const int* dstArr = ei + N_EDGES;  // row 1

    float* ws = (float*)d_ws;
    size_t off = 0;
    auto alloc = [&](size_t nf) { float* p = ws + off; off += (nf + 63) & ~(size_t)63; return p; };
    float* xl        = alloc((size_t)N_NODES * FEAT);
    float* xr        = alloc((size_t)N_NODES * FEAT);
    float* h         = alloc((size_t)N_NODES * FEAT);
    float* loop_attr = alloc((size_t)N_NODES * ED_DIM);
    float* gpool     = alloc((size_t)BATCH * FEAT);
    int* ibase  = (int*)(ws + off);
    int* deg    = ibase;
    int* fill   = ibase + N_NODES;
    int* rowptr = ibase + 2 * N_NODES;            // N+1 ints
    int* bsum   = ibase + 3 * N_NODES + 64;
    int* boff   = bsum + 256;
    int2* elist2 = (int2*)(boff + 256);           // ETOT int2

    // aliases at disjoint lifetimes
    float* ghid = xl;                       // after L3 gat, xl is dead
    float* gate = xr;

    hipMemsetAsync(deg, 0, (size_t)2 * N_NODES * sizeof(int), stream);

    // CSR build, then self-loop mean attrs from CSR
    k_deg<<<(ETOT + 255) / 256, 256, 0, stream>>>(dstArr, deg);
    k_scan1<<<NCHUNK, 256, 0, stream>>>(deg, bsum);
    k_scan2<<<1, 256, 0, stream>>>(bsum, boff, rowptr);
    k_scan3<<<NCHUNK, 256, 0, stream>>>(deg, boff, rowptr);
    k_fill<<<(ETOT + 255) / 256, 256, 0, stream>>>(srcArr, dstArr, rowptr, fill, elist2);
    k_loop_csr<<<(N_NODES * ED_DIM + 255) / 256, 256, 0, stream>>>(elist2, rowptr, ea, loop_attr);

    // layer 1 (in: x [N,128])
    launch_gemm(x, c1_Wl, c1_bl, xl, N_NODES, FEAT, IN_DIM, 0, stream);
    launch_gemm(x, c1_Wr, c1_br, xr, N_NODES, FEAT, IN_DIM, 0, stream);
    k_gat<4, 1><<<N_NODES / 4, 256, 0, stream>>>(xl, xr, ea, loop_attr, elist2, rowptr,
                                                 c1_We, c1_att, c1_bias, h);
    // layer 2
    launch_gemm(h, c2_Wl, c2_bl, xl, N_NODES, FEAT, FEAT, 0, stream);
    launch_gemm(h, c2_Wr, c2_br, xr, N_NODES, FEAT, FEAT, 0, stream);
    k_gat<4, 1><<<N_NODES / 4, 256, 0, stream>>>(xl, xr, ea, loop_attr, elist2, rowptr,
                                                 c2_We, c2_att, c2_bias, h);
    // layer 3 (heads=1, no relu)
    launch_gemm(h, c3_Wl, c3_bl, xl, N_NODES, FEAT, FEAT, 0, stream);
    launch_gemm(h, c3_Wr, c3_br, xr, N_NODES, FEAT, FEAT, 0, stream);
    k_gat<1, 0><<<N_NODES / 4, 256, 0, stream>>>(xl, xr, ea, loop_attr, elist2, rowptr,
                                                 c3_We, c3_att, c3_bias, h);

    // pooling + head
    launch_gemm(h, gate_W1, gate_b1, ghid, N_NODES, 128, FEAT, 1, stream);
    k_gate_score<<<N_NODES / 4, 256, 0, stream>>>(ghid, gate_W2, gate_b2, gate);
    k_pool<<<BATCH, 256, 0, stream>>>(gate, h, batch, gpool);
    k_reg<<<BATCH, 128, 0, stream>>>(gpool, reg_W1, reg_b1, reg_W2, reg_b2, (float*)d_out);
}